// Round 1
// baseline (399.038 us; speedup 1.0000x reference)
//
#include <hip/hip_runtime.h>
#include <stdint.h>

typedef short bf16x8 __attribute__((ext_vector_type(8)));
typedef float f32x4 __attribute__((ext_vector_type(4)));
typedef unsigned short u16;
typedef unsigned short u16x4 __attribute__((ext_vector_type(4)));
typedef unsigned short u16x8 __attribute__((ext_vector_type(8)));

#define LOG2E 1.44269504088896f

// sizes
#define Bz 4
#define Sz 2048
#define Hz 1024
#define NHz 16
#define HDz 64
#define BHz (Bz*NHz)      // 64
#define NCOL 3200         // 1024*3 + 128

__device__ __forceinline__ u16 f2bf(float f) {
  uint32_t u = __builtin_bit_cast(uint32_t, f);
  u += 0x7fffu + ((u >> 16) & 1u);
  return (u16)(u >> 16);
}
__device__ __forceinline__ float bf2f(u16 h) {
  uint32_t u = ((uint32_t)h) << 16;
  return __builtin_bit_cast(float, u);
}

__device__ __forceinline__ void gll16(const void* g, void* l) {
  __builtin_amdgcn_global_load_lds((const __attribute__((address_space(1))) void*)g,
                                   (__attribute__((address_space(3))) void*)l,
                                   16, 0, 0);
}

// ---------------- X (f32) -> bf16 ----------------
__global__ void k_cvt_x(const float* __restrict__ X, u16* __restrict__ Xb) {
  int i = blockIdx.x * 256 + threadIdx.x;   // 2097152 threads, 4 elems each
  float4 v = ((const float4*)X)[i];
  u16x4 r;
  r[0] = f2bf(v.x); r[1] = f2bf(v.y); r[2] = f2bf(v.z); r[3] = f2bf(v.w);
  ((u16x4*)Xb)[i] = r;
}

// ------- pack & transpose [Wq|Wk|Wv|Ws] -> Wt[3200][1024] bf16 -------
__global__ void k_cvt_w(const float* __restrict__ Wq, const float* __restrict__ Wk,
                        const float* __restrict__ Wv, const float* __restrict__ Ws,
                        u16* __restrict__ Wt) {
  __shared__ float tile[64][65];
  int n0 = blockIdx.x * 64, k0 = blockIdx.y * 64;
  const float* src; int ld, c0;
  if (n0 < 1024)      { src = Wq; ld = 1024; c0 = n0; }
  else if (n0 < 2048) { src = Wk; ld = 1024; c0 = n0 - 1024; }
  else if (n0 < 3072) { src = Wv; ld = 1024; c0 = n0 - 2048; }
  else                { src = Ws; ld = 128;  c0 = n0 - 3072; }
  int t = threadIdx.x;
  #pragma unroll
  for (int i = 0; i < 16; ++i) {
    int idx = t + i * 256; int r = idx >> 6, c = idx & 63;
    tile[r][c] = src[(size_t)(k0 + r) * ld + c0 + c];
  }
  __syncthreads();
  #pragma unroll
  for (int i = 0; i < 16; ++i) {
    int idx = t + i * 256; int rn = idx >> 6, ck = idx & 63;
    Wt[(size_t)(n0 + rn) * 1024 + k0 + ck] = f2bf(tile[ck][rn]);
  }
}

// ---------------- fused QKV+S GEMM: [8192,1024] x [1024,3200] ----------------
// A = Xb row-major [8192][1024]; B^T = Wt [3200][1024]. 128x128 tile, BK=32.
__launch_bounds__(256)
__global__ void k_gemm(const u16* __restrict__ Xb, const u16* __restrict__ Wt,
                       const float* __restrict__ bq, const float* __restrict__ bk,
                       const float* __restrict__ bv, const float* __restrict__ bs,
                       u16* __restrict__ Qw, u16* __restrict__ Kw, u16* __restrict__ Vw,
                       float* __restrict__ Sw) {
  __shared__ u16 As[128 * 32];
  __shared__ u16 Bs[128 * 32];
  int t = threadIdx.x, lane = t & 63;
  int wave = t >> 6, wr = wave >> 1, wc = wave & 1;
  int m0 = blockIdx.y * 128, n0 = blockIdx.x * 128;

  f32x4 acc[4][4];
  #pragma unroll
  for (int i = 0; i < 4; ++i)
    #pragma unroll
    for (int j = 0; j < 4; ++j) { f32x4 z = {0.f,0.f,0.f,0.f}; acc[i][j] = z; }

  int srow = t >> 2;              // 0..63
  int sobyte = (t & 3) << 4;      // 0,16,32,48

  for (int kt = 0; kt < 32; ++kt) {
    int kb = kt * 64;             // byte offset along k
    #pragma unroll
    for (int c = 0; c < 2; ++c) {
      int row = c * 64 + srow;
      int sb = sobyte ^ ((row & 3) << 4);    // swizzled source col (64B rows)
      gll16((const char*)(Xb + (size_t)(m0 + row) * 1024) + kb + sb,
            (char*)As + row * 64 + sobyte);
    }
    #pragma unroll
    for (int c = 0; c < 2; ++c) {
      int row = c * 64 + srow;
      int sb = sobyte ^ ((row & 3) << 4);
      gll16((const char*)(Wt + (size_t)(n0 + row) * 1024) + kb + sb,
            (char*)Bs + row * 64 + sobyte);
    }
    __syncthreads();
    bf16x8 af[4], bfr[4];
    #pragma unroll
    for (int ai = 0; ai < 4; ++ai) {
      int row = wr * 64 + ai * 16 + (lane & 15);
      int bo = row * 64 + ((((lane >> 4) << 4)) ^ ((row & 3) << 4));
      af[ai] = *(const bf16x8*)((const char*)As + bo);
    }
    #pragma unroll
    for (int bj = 0; bj < 4; ++bj) {
      int row = wc * 64 + bj * 16 + (lane & 15);
      int bo = row * 64 + ((((lane >> 4) << 4)) ^ ((row & 3) << 4));
      bfr[bj] = *(const bf16x8*)((const char*)Bs + bo);
    }
    #pragma unroll
    for (int ai = 0; ai < 4; ++ai)
      #pragma unroll
      for (int bj = 0; bj < 4; ++bj)
        acc[ai][bj] = __builtin_amdgcn_mfma_f32_16x16x32_bf16(af[ai], bfr[bj], acc[ai][bj], 0, 0, 0);
    __syncthreads();
  }

  // epilogue: route Q/K/V (bf16, [b,h,s,d]) and scale head
  #pragma unroll
  for (int ai = 0; ai < 4; ++ai) {
    #pragma unroll
    for (int bj = 0; bj < 4; ++bj) {
      #pragma unroll
      for (int r = 0; r < 4; ++r) {
        int m = m0 + wr * 64 + ai * 16 + ((lane >> 4) << 2) + r;
        int j = n0 + wc * 64 + bj * 16 + (lane & 15);
        float v = acc[ai][bj][r];
        int b = m >> 11, si = m & 2047;
        if (j < 3072) {
          float bias = (j < 1024) ? bq[j] : (j < 2048) ? bk[j - 1024] : bv[j - 2048];
          v += bias;
          int jj = j & 1023, h = jj >> 6, d = jj & 63;
          size_t dst = (((size_t)(b * NHz + h) * Sz + si) << 6) + d;
          u16 hv = f2bf(v);
          if (j < 1024) Qw[dst] = hv;
          else if (j < 2048) Kw[dst] = hv;
          else Vw[dst] = hv;
        } else {
          int c = j - 3072;
          v += bs[c];
          float sig = 1.0f / (1.0f + __expf(-v));
          // fold softmax 1/sqrt(64) into the Q scale
          Sw[(size_t)m * 128 + c] = (0.9f + 0.2f * sig) * 0.125f;
        }
      }
    }
  }
}

// ---------------- Q *= s (per head,group), s includes 0.125 ----------------
__global__ void k_scale_q(u16* __restrict__ Qw, const float* __restrict__ Sw) {
  int tid = blockIdx.x * 256 + threadIdx.x;   // 1048576 threads, 8 elems each
  size_t base = (size_t)tid * 8;
  int bh = (int)(base >> 17);
  int si = (int)((base >> 6) & 2047);
  int d0 = (int)(base & 63);
  int b = bh >> 4, h = bh & 15;
  float s = Sw[((size_t)(b * Sz + si)) * 128 + h * 8 + (d0 >> 3)];
  u16x8 v = *(u16x8*)(Qw + base);
  #pragma unroll
  for (int j = 0; j < 8; ++j) v[j] = f2bf(bf2f(v[j]) * s);
  *(u16x8*)(Qw + base) = v;
}

// ---------------- V [bh][s][d] -> Vt [bh][d][s] ----------------
__global__ void k_trans_v(const u16* __restrict__ Vw, u16* __restrict__ Vt) {
  __shared__ u16 tile[64][65];
  int bh = blockIdx.y, s0 = blockIdx.x * 64;
  int t = threadIdx.x;
  const u16* src = Vw + ((size_t)bh * Sz + s0) * 64;
  #pragma unroll
  for (int i = 0; i < 16; ++i) {
    int idx = t + i * 256; int r = idx >> 6, c = idx & 63;
    tile[r][c] = src[r * 64 + c];
  }
  __syncthreads();
  u16* dst = Vt + (size_t)bh * 64 * Sz;
  #pragma unroll
  for (int i = 0; i < 16; ++i) {
    int idx = t + i * 256; int d = idx >> 6, ss = idx & 63;
    dst[(size_t)d * Sz + s0 + ss] = tile[ss][d];
  }
}

// ---------------- flash attention ----------------
// grid (32 q-tiles, 64 bh); 4 waves x 16 q-rows; KVBLK=64.
__launch_bounds__(256)
__global__ void k_attn(const u16* __restrict__ Qw, const u16* __restrict__ Kw,
                       const u16* __restrict__ Vt, float* __restrict__ out) {
  __shared__ u16 Kl[64 * 64];        // [kv][d], xor-swizzled 128B rows
  __shared__ u16 Vl[64 * 64];        // [d][kv], xor-swizzled
  __shared__ u16 Pl[4][16 * 64];     // per-wave [q][kv], xor-swizzled

  int t = threadIdx.x, lane = t & 63, wave = t >> 6;
  int bh = blockIdx.y;
  int q0 = blockIdx.x * 64 + wave * 16;

  // Q fragments (k-slices ks=0,1), rows = q0 + (lane&15)
  const u16* Qp = Qw + ((size_t)bh * Sz + q0 + (lane & 15)) * 64 + ((lane >> 4) << 3);
  bf16x8 qf0 = *(const bf16x8*)Qp;
  bf16x8 qf1 = *(const bf16x8*)(Qp + 32);

  float mrow[4] = {-1e30f, -1e30f, -1e30f, -1e30f};
  float lrow[4] = {0.f, 0.f, 0.f, 0.f};
  f32x4 o[4];
  #pragma unroll
  for (int i = 0; i < 4; ++i) { f32x4 z = {0.f,0.f,0.f,0.f}; o[i] = z; }

  int srow = t >> 3;              // 0..31
  int sobyte = (t & 7) << 4;      // 0..112
  const char* Kg = (const char*)(Kw + (size_t)bh * Sz * 64);
  const char* Vg = (const char*)(Vt + (size_t)bh * 64 * Sz);

  for (int kv0 = 0; kv0 < Sz; kv0 += 64) {
    __syncthreads();   // previous iteration's LDS reads complete
    #pragma unroll
    for (int c = 0; c < 2; ++c) {
      int row = c * 32 + srow;
      int sb = sobyte ^ ((row & 7) << 4);
      gll16(Kg + (size_t)(kv0 + row) * 128 + sb, (char*)Kl + row * 128 + sobyte);
      gll16(Vg + (size_t)row * (Sz * 2) + (size_t)kv0 * 2 + sb, (char*)Vl + row * 128 + sobyte);
    }
    __syncthreads();   // staged tiles visible

    // QK^T: sc[nt] covers kv cols nt*16..+15
    f32x4 sc[4];
    #pragma unroll
    for (int nt = 0; nt < 4; ++nt) {
      int row = nt * 16 + (lane & 15);
      int cb0 = (lane >> 4) << 4;
      bf16x8 kf0 = *(const bf16x8*)((const char*)Kl + row * 128 + (cb0 ^ ((row & 7) << 4)));
      bf16x8 kf1 = *(const bf16x8*)((const char*)Kl + row * 128 + ((64 + cb0) ^ ((row & 7) << 4)));
      f32x4 a = {0.f,0.f,0.f,0.f};
      a = __builtin_amdgcn_mfma_f32_16x16x32_bf16(qf0, kf0, a, 0, 0, 0);
      a = __builtin_amdgcn_mfma_f32_16x16x32_bf16(qf1, kf1, a, 0, 0, 0);
      sc[nt] = a;
    }

    // online softmax (rows live in 16-lane groups; reduce across lanes)
    #pragma unroll
    for (int r = 0; r < 4; ++r) {
      float mx = fmaxf(fmaxf(sc[0][r], sc[1][r]), fmaxf(sc[2][r], sc[3][r]));
      mx = fmaxf(mx, __shfl_xor(mx, 1));
      mx = fmaxf(mx, __shfl_xor(mx, 2));
      mx = fmaxf(mx, __shfl_xor(mx, 4));
      mx = fmaxf(mx, __shfl_xor(mx, 8));
      float mn = fmaxf(mrow[r], mx);
      float f = exp2f((mrow[r] - mn) * LOG2E);
      mrow[r] = mn;
      float ps = 0.f;
      #pragma unroll
      for (int nt = 0; nt < 4; ++nt) {
        float p = exp2f((sc[nt][r] - mn) * LOG2E);
        sc[nt][r] = p;
        ps += p;
      }
      ps += __shfl_xor(ps, 1); ps += __shfl_xor(ps, 2);
      ps += __shfl_xor(ps, 4); ps += __shfl_xor(ps, 8);
      lrow[r] = lrow[r] * f + ps;
      #pragma unroll
      for (int nt = 0; nt < 4; ++nt) o[nt][r] *= f;
    }

    // P -> wave-private LDS (bf16), C-frag layout -> A-frag layout
    #pragma unroll
    for (int r = 0; r < 4; ++r) {
      int q = ((lane >> 4) << 2) + r;
      #pragma unroll
      for (int nt = 0; nt < 4; ++nt) {
        int kv = nt * 16 + (lane & 15);
        *(u16*)((char*)Pl[wave] + q * 128 + ((kv * 2) ^ ((q & 7) << 4))) = f2bf(sc[nt][r]);
      }
    }
    asm volatile("s_waitcnt lgkmcnt(0)" ::: "memory");

    // PV: o[nt] += P(16x64) @ V(64x64) for d-block nt
    #pragma unroll
    for (int ks = 0; ks < 2; ++ks) {
      int q = lane & 15;
      int colb = ks * 64 + ((lane >> 4) << 4);
      bf16x8 pa = *(const bf16x8*)((const char*)Pl[wave] + q * 128 + (colb ^ ((q & 7) << 4)));
      #pragma unroll
      for (int nt = 0; nt < 4; ++nt) {
        int row = nt * 16 + (lane & 15);
        bf16x8 vf = *(const bf16x8*)((const char*)Vl + row * 128 + (colb ^ ((row & 7) << 4)));
        o[nt] = __builtin_amdgcn_mfma_f32_16x16x32_bf16(pa, vf, o[nt], 0, 0, 0);
      }
    }
  }

  // epilogue: out[b, s, h*64+d] = o / l
  int b = bh >> 4, h = bh & 15;
  #pragma unroll
  for (int nt = 0; nt < 4; ++nt) {
    #pragma unroll
    for (int r = 0; r < 4; ++r) {
      int q = ((lane >> 4) << 2) + r;
      out[((size_t)b * Sz + q0 + q) * (NHz * HDz) + h * 64 + nt * 16 + (lane & 15)] =
          o[nt][r] / lrow[r];
    }
  }
}

extern "C" void kernel_launch(void* const* d_in, const int* in_sizes, int n_in,
                              void* d_out, int out_size, void* d_ws, size_t ws_size,
                              hipStream_t stream) {
  const float* X  = (const float*)d_in[0];
  const float* Wq = (const float*)d_in[1];
  const float* bq = (const float*)d_in[2];
  const float* Wk = (const float*)d_in[3];
  const float* bk = (const float*)d_in[4];
  const float* Wv = (const float*)d_in[5];
  const float* bv = (const float*)d_in[6];
  const float* Ws = (const float*)d_in[7];
  const float* bs = (const float*)d_in[8];
  float* out = (float*)d_out;

  // ws: Qw | Kw | Vw | Vt  (16 MB each, bf16 [bh][s][d] / [bh][d][s])
  char* ws = (char*)d_ws;
  u16* Qw = (u16*)(ws);
  u16* Kw = (u16*)(ws + (size_t)(16u << 20));
  u16* Vw = (u16*)(ws + (size_t)(32u << 20));
  u16* Vt = (u16*)(ws + (size_t)(48u << 20));

  // d_out doubles as scratch for Xb (16MB) | Wt (6.55MB @ +16MB) | Sw (4MB @ +24MB);
  // all are dead before k_attn overwrites the full output.
  char* ob = (char*)d_out;
  u16* Xb   = (u16*)ob;
  u16* Wt   = (u16*)(ob + (size_t)(16u << 20));
  float* Sw = (float*)(ob + (size_t)(24u << 20));

  k_cvt_x<<<8192, 256, 0, stream>>>(X, Xb);
  k_cvt_w<<<dim3(50, 16), 256, 0, stream>>>(Wq, Wk, Wv, Ws, Wt);
  k_gemm<<<dim3(25, 64), 256, 0, stream>>>(Xb, Wt, bq, bk, bv, bs, Qw, Kw, Vw, Sw);
  k_scale_q<<<4096, 256, 0, stream>>>(Qw, Sw);
  k_trans_v<<<dim3(32, 64), 256, 0, stream>>>(Vw, Vt);
  k_attn<<<dim3(32, 64), 256, 0, stream>>>(Qw, Kw, Vt, out);
}